// Round 6
// baseline (166.885 us; speedup 1.0000x reference)
//
#include <hip/hip_runtime.h>
#include <hip/hip_bf16.h>

#define B_ 2
#define S_ 2048
#define D_ 1024
#define H_ 16
#define HD_ 64

typedef __attribute__((ext_vector_type(8))) short short8;
typedef __attribute__((ext_vector_type(4))) short short4v;
typedef __attribute__((ext_vector_type(4))) float float4v;

typedef const __attribute__((address_space(1))) void* gas_ptr;
typedef __attribute__((address_space(3))) void* las_ptr;

static __device__ inline void gl_lds16(const void* g, void* l) {
  __builtin_amdgcn_global_load_lds((gas_ptr)g, (las_ptr)l, 16, 0, 0);
}

static __device__ inline short f2bs(float x) {
  __hip_bfloat16 h = __float2bfloat16(x);
  union { __hip_bfloat16 h; short s; } u; u.h = h; return u.s;
}
static __device__ inline float bs2f(short s) {
  union { short s; __hip_bfloat16 h; } u; u.s = s; return __bfloat162float(u.h);
}
// packed f32x4 -> bf16x4 (v_cvt_pk_bf16_f32 x2)
static __device__ inline short4v pk4(float a, float b, float c, float d) {
  union { __hip_bfloat162 h[2]; short4v s; } u;
  u.h[0] = __float22bfloat162_rn(float2{a, b});
  u.h[1] = __float22bfloat162_rn(float2{c, d});
  return u.s;
}

static __device__ inline float4v mfma32(short8 a, short8 b, float4v c) {
  return __builtin_amdgcn_mfma_f32_16x16x32_bf16(a, b, c, 0, 0, 0);
}
// v_mfma_f32_16x16x16_bf16 — "_1k" builtin, present on gfx950.
static __device__ inline float4v mfma16(short4v a, short4v b, float4v c) {
  return __builtin_amdgcn_mfma_f32_16x16x16bf16_1k(a, b, c, 0, 0, 0);
}

// ------- Stage A (merged): blocks [0,2048): hs fp32->bf16; blocks [2048,2560):
// W fp32 [k][n] -> Wt bf16 [n][k]. -------
__global__ __launch_bounds__(256) void prep(
    const float* __restrict__ hs, __hip_bfloat16* __restrict__ hsb,
    const float* __restrict__ Wq, const float* __restrict__ Wk,
    __hip_bfloat16* __restrict__ Wqt, __hip_bfloat16* __restrict__ Wkt) {
  __shared__ float t[64][65];
  const int id = blockIdx.x;
  if (id < 2048) {
    const size_t i = ((size_t)id * 256 + threadIdx.x) * 8;
    const float4v a0 = ((const float4v*)(hs + i))[0];
    const float4v a1 = ((const float4v*)(hs + i))[1];
    short8 s;
#pragma unroll
    for (int j = 0; j < 4; ++j) { s[j] = f2bs(a0[j]); s[4 + j] = f2bs(a1[j]); }
    *(short8*)(hsb + i) = s;
    return;
  }
  const int bid = id - 2048;
  const float* W = (bid >> 8) ? Wk : Wq;
  __hip_bfloat16* Wt = (bid >> 8) ? Wkt : Wqt;
  const int n0 = (bid & 15) * 64, k0 = ((bid >> 4) & 15) * 64;
  const int c = threadIdx.x & 63, r0 = threadIdx.x >> 6;
  for (int i = 0; i < 16; ++i) {
    const int r = i * 4 + r0;
    t[c][r] = W[(size_t)(k0 + r) * D_ + n0 + c];
  }
  __syncthreads();
  for (int i = 0; i < 16; ++i) {
    const int rr = i * 4 + r0;
    Wt[(size_t)(n0 + rr) * D_ + k0 + c] = __float2bfloat16(t[rr][c]);
  }
}

// ---- Stage B (fused GEMM+prep): r18 structure, unchanged (attribution). ----
__global__ __launch_bounds__(256, 2) void gemm_fused(
    const __hip_bfloat16* __restrict__ hsb,
    const __hip_bfloat16* __restrict__ Wqt, const __hip_bfloat16* __restrict__ Wkt,
    const float* __restrict__ bq, const float* __restrict__ bk,
    __hip_bfloat16* __restrict__ q_out, __hip_bfloat16* __restrict__ kt_out,
    __hip_bfloat16* __restrict__ vT) {
  const int id = blockIdx.x;
  const int mt = (id & 7) * 8 + ((id >> 3) & 7);  // m-tile 0..63, pinned by xcd
  const int nt = id >> 6;                          // n-block 0..7
  const int n0 = nt * 128, m0 = mt * 64;
  __shared__ __hip_bfloat16 As[2][64 * 32];    // 8KB
  __shared__ __hip_bfloat16 Bq[2][128 * 32];   // 16KB
  __shared__ __hip_bfloat16 Bk[2][128 * 32];   // 16KB
  const int tid = threadIdx.x, wid = tid >> 6, lane = tid & 63;
  const int wm = (wid >> 1) * 32, wn = (wid & 1) * 64;
  const int l15 = lane & 15, l4 = lane >> 4;
  const float4v zz = {0.f, 0.f, 0.f, 0.f};
  float4v accq[2][4], acck[2][4];
  for (int i = 0; i < 2; ++i)
    for (int j = 0; j < 4; ++j) { accq[i][j] = zz; acck[i][j] = zz; }
  const int lrow = wid * 16 + (lane >> 2);
  const int lk8 = (((lane & 3) ^ ((lane >> 3) & 3)) * 8);
  {
    gl_lds16(hsb + (size_t)(m0 + lrow) * D_ + lk8, As[0] + wid * 512);
    gl_lds16(Wqt + (size_t)(n0 + lrow) * D_ + lk8, Bq[0] + wid * 512);
    gl_lds16(Wqt + (size_t)(n0 + 64 + lrow) * D_ + lk8, Bq[0] + 2048 + wid * 512);
    gl_lds16(Wkt + (size_t)(n0 + lrow) * D_ + lk8, Bk[0] + wid * 512);
    gl_lds16(Wkt + (size_t)(n0 + 64 + lrow) * D_ + lk8, Bk[0] + 2048 + wid * 512);
  }
  int p = 0;
  for (int kb = 0; kb < 32; ++kb) {
    __syncthreads();  // buf[p] staged (vm drained); prev frag reads done
    if (kb < 31) {
      const int kc = (kb + 1) * 32 + lk8;
      gl_lds16(hsb + (size_t)(m0 + lrow) * D_ + kc, As[p ^ 1] + wid * 512);
      gl_lds16(Wqt + (size_t)(n0 + lrow) * D_ + kc, Bq[p ^ 1] + wid * 512);
      gl_lds16(Wqt + (size_t)(n0 + 64 + lrow) * D_ + kc, Bq[p ^ 1] + 2048 + wid * 512);
      gl_lds16(Wkt + (size_t)(n0 + lrow) * D_ + kc, Bk[p ^ 1] + wid * 512);
      gl_lds16(Wkt + (size_t)(n0 + 64 + lrow) * D_ + kc, Bk[p ^ 1] + 2048 + wid * 512);
    }
    short8 af[2], bfq[4], bfk[4];
    const int fo = ((l4 ^ ((l15 >> 1) & 3)) * 8);  // de-swizzle on read
    for (int rt = 0; rt < 2; ++rt)
      af[rt] = *(const short8*)(As[p] + (wm + rt * 16 + l15) * 32 + fo);
    for (int ct = 0; ct < 4; ++ct) {
      bfq[ct] = *(const short8*)(Bq[p] + (wn + ct * 16 + l15) * 32 + fo);
      bfk[ct] = *(const short8*)(Bk[p] + (wn + ct * 16 + l15) * 32 + fo);
    }
    for (int rt = 0; rt < 2; ++rt)
      for (int ct = 0; ct < 4; ++ct) {
        accq[rt][ct] = mfma32(af[rt], bfq[ct], accq[rt][ct]);
        acck[rt][ct] = mfma32(af[rt], bfk[ct], acck[rt][ct]);
      }
    p ^= 1;
  }
  float bvq[4], bvk[4];
  for (int ct = 0; ct < 4; ++ct) {
    bvq[ct] = bq[n0 + wn + ct * 16 + l15];
    bvk[ct] = bk[n0 + wn + ct * 16 + l15];
  }
  for (int rt = 0; rt < 2; ++rt)
    for (int ct = 0; ct < 4; ++ct) {
      const int col = n0 + wn + ct * 16 + l15;
      const int h = col >> 6, d = col & 63;
      const int rowb = m0 + wm + rt * 16 + l4 * 4;
      short4v vv;
      for (int r = 0; r < 4; ++r) {
        const int row = rowb + r;
        const float qv = accq[rt][ct][r] + bvq[ct];
        const float kv = acck[rt][ct][r] + bvk[ct];
        const float sp = fmaxf(kv, 0.f) + __logf(1.f + __expf(-fabsf(kv)));
        q_out[(size_t)row * D_ + col] = __float2bfloat16(qv);
        kt_out[(size_t)row * D_ + col] = __float2bfloat16(sp);
        vv[r] = f2bs(qv + kv);
      }
      const int b = rowb >> 11, s = rowb & 2047;
      // key swizzle p(k) within 64-chunk; s%4==0 -> 4 consecutive stay together
      const int sw = (s & ~63) | (((s >> 4) & 3) << 2) | (((s >> 2) & 3) << 4);
      *(short4v*)(vT + ((size_t)(b * H_ + h) * HD_ + d) * S_ + sw) = vv;
    }
}

// ------- Stage D: flash attention — r21 KEY-SPLIT-ACROSS-BLOCKS (decode style).
// r20 verdict: conflict counter = 4/ds_read_b128 artifact (confirmed); halving
// LDS reads gained only 1.3us -> latency-bound at 2 waves/SIMD (grid 512 =
// 2 blocks/CU). Fix: grid 1024 = 512 pairs x 2 key-ranges of 1024 keys.
// 64-key chunks (dbuf 32KB) + mbuf 34KB -> ~35KB LDS -> 4 blocks/CU; ALL
// 1024 blocks co-resident -> 4 waves/SIMD (2x TLP). Wave = 32 q-rows x full
// chunk: total LDS reads unchanged vs r20 (524288); VGPR ~115 <= 128 cap;
// epilogue loses the kh-combine. Partial O (f32) + l -> workspace; comb
// kernel normalizes. Partials overlay Wqt/Wkt/hsb (dead after gemm).
__global__ __launch_bounds__(256, 4) void attn(
    const __hip_bfloat16* __restrict__ qb, const __hip_bfloat16* __restrict__ ktb,
    const __hip_bfloat16* __restrict__ vT, const int* __restrict__ mask,
    float* __restrict__ po, float* __restrict__ pl) {
  // dbuf: 2 x (K 4096 + V 4096) shorts = 32KB; epilogue mbuf[128][68] f32 = 34816B
  __shared__ short smem[17408];
  const int id = blockIdx.x;
  const int xcd = id & 7;
  const int rest = id >> 3;              // 0..127
  const int qt = rest & 15;
  const int kr = (rest >> 4) & 1;        // key-range half
  const int hb = (rest >> 5) * 8 + xcd;  // 0..31 (same-head q-tiles share XCD)
  const int h = hb >> 1, b = hb & 1;
  const int q0 = qt * 128;
  const int k0 = kr * 1024;
  const int pid = hb * 16 + qt;          // 0..511 (kr-independent pair id)
  const int tid = threadIdx.x, wid = tid >> 6, lane = tid & 63;
  const int l15 = lane & 15, l4 = lane >> 4;
  const int qs = wid * 32;               // wave's 32 q-rows (2 tiles)
  const __hip_bfloat16* qh = qb + (size_t)b * S_ * D_ + h * HD_;
  const __hip_bfloat16* kh_ = ktb + (size_t)b * S_ * D_ + h * HD_;
  const __hip_bfloat16* vh = vT + (size_t)(b * H_ + h) * HD_ * S_;
  // staging map: row=tid>>2 (0..63), two 16B blocks b0=(tid&3), b0+4
  const int srow = tid >> 2;
  const int b0 = tid & 3;
  const int ssw = ((srow & 1) << 2) | ((srow >> 1) & 3);  // s(row)
  const int w0 = srow * 64 + ((b0 ^ ssw) * 8);
  const int w1 = srow * 64 + (((b0 + 4) ^ ssw) * 8);

  // Q B-fragments for the wave's 2 q-tiles; mask*scale*log2e folded in
  const float SC = 0.125f * 1.44269504f;
  short8 bq0[2], bq1[2];
#pragma unroll
  for (int T = 0; T < 2; ++T) {
    const int qr = q0 + qs + T * 16 + l15;
    const float mq = (mask[b * S_ + qr] != 0) ? SC : 0.f;
    const short8 r0 = *(const short8*)(qh + (size_t)qr * D_ + l4 * 8);
    const short8 r1 = *(const short8*)(qh + (size_t)qr * D_ + 32 + l4 * 8);
#pragma unroll
    for (int j = 0; j < 8; ++j) {
      bq0[T][j] = f2bs(bs2f(r0[j]) * mq);
      bq1[T][j] = f2bs(bs2f(r1[j]) * mq);
    }
  }

  // fragment read offsets (s(row)-swizzled; row&7 == l15&7 for all reads)
  const int lsw = ((l15 & 1) << 2) | ((l15 >> 1) & 3);
  const int ak0off = l15 * 64 + ((l4 ^ lsw) * 8);          // + t*1024
  const int ak1off = l15 * 64 + (((l4 + 4) ^ lsw) * 8);
  const int vb0off = ((2 * l4) ^ lsw) * 8;                 // + row*64
  const int vb1off = ((2 * l4 + 1) ^ lsw) * 8;

  const float4v zz = {0.f, 0.f, 0.f, 0.f};
  float4v oacc[2][4];  // [T][dt]
#pragma unroll
  for (int T = 0; T < 2; ++T)
#pragma unroll
    for (int dt = 0; dt < 4; ++dt) oacc[T][dt] = zz;
  float4v ls[2] = {zz, zz};  // per-T, per-r partial sums

  // prefetch chunk 0 (64 keys)
  short8 gk0, gk1, gv0, gv1;
  gk0 = *(const short8*)(kh_ + (size_t)(k0 + srow) * D_ + b0 * 8);
  gk1 = *(const short8*)(kh_ + (size_t)(k0 + srow) * D_ + b0 * 8 + 32);
  gv0 = *(const short8*)(vh + (size_t)srow * S_ + k0 + b0 * 8);
  gv1 = *(const short8*)(vh + (size_t)srow * S_ + k0 + b0 * 8 + 32);

  int pb = 0;
  for (int c = 0; c < 16; ++c) {
    short* bufp = smem + pb * 8192;      // K at 0, V at 4096
    *(short8*)(bufp + w0) = gk0;
    *(short8*)(bufp + w1) = gk1;
    *(short8*)(bufp + 4096 + w0) = gv0;
    *(short8*)(bufp + 4096 + w1) = gv1;
    __syncthreads();
    if (c < 15) {
      const int kb = k0 + (c + 1) * 64;
      gk0 = *(const short8*)(kh_ + (size_t)(kb + srow) * D_ + b0 * 8);
      gk1 = *(const short8*)(kh_ + (size_t)(kb + srow) * D_ + b0 * 8 + 32);
      gv0 = *(const short8*)(vh + (size_t)srow * S_ + kb + b0 * 8);
      gv1 = *(const short8*)(vh + (size_t)srow * S_ + kb + b0 * 8 + 32);
    }
    const short* kbase = bufp;
    const short* vbase = bufp + 4096;
    // ---- phase 1: QK, 4 key-tiles x 2 q-tiles -> P fragments (exp2 domain)
    short4v pf[2][4];  // [T][t]
#pragma unroll
    for (int t = 0; t < 4; ++t) {
      const short8 ak0 = *(const short8*)(kbase + t * 1024 + ak0off);
      const short8 ak1 = *(const short8*)(kbase + t * 1024 + ak1off);
#pragma unroll
      for (int T = 0; T < 2; ++T) {
        float4v cc = zz;
        cc = mfma32(ak0, bq0[T], cc);
        cc = mfma32(ak1, bq1[T], cc);
        float e[4];
#pragma unroll
        for (int r = 0; r < 4; ++r) {
          e[r] = __builtin_amdgcn_exp2f(cc[r]); ls[T][r] += e[r];
        }
        pf[T][t] = pk4(e[0], e[1], e[2], e[3]);
      }
    }
    // ---- phase 2: PV over the chunk's 64 keys ----
#pragma unroll
    for (int dt = 0; dt < 4; ++dt) {
      const int rb = (dt * 16 + l15) * 64;
      const short8 av0 = *(const short8*)(vbase + rb + vb0off);
      const short8 av1 = *(const short8*)(vbase + rb + vb1off);
      const short4v a0 = {av0[0], av0[1], av0[2], av0[3]};
      const short4v a1 = {av0[4], av0[5], av0[6], av0[7]};
      const short4v a2 = {av1[0], av1[1], av1[2], av1[3]};
      const short4v a3 = {av1[4], av1[5], av1[6], av1[7]};
#pragma unroll
      for (int T = 0; T < 2; ++T) {
        oacc[T][dt] = mfma16(a0, pf[T][0], oacc[T][dt]);
        oacc[T][dt] = mfma16(a1, pf[T][1], oacc[T][dt]);
        oacc[T][dt] = mfma16(a2, pf[T][2], oacc[T][dt]);
        oacc[T][dt] = mfma16(a3, pf[T][3], oacc[T][dt]);
      }
    }
    pb ^= 1;
  }
  // ---- epilogue: per-row l -> global; O transpose via mbuf -> partial out ----
  float lT[2];
#pragma unroll
  for (int T = 0; T < 2; ++T) {
    lT[T] = (ls[T][0] + ls[T][1]) + (ls[T][2] + ls[T][3]);
    lT[T] += __shfl_xor(lT[T], 16);
    lT[T] += __shfl_xor(lT[T], 32);
  }
  __syncthreads();  // all dbuf reads done before mbuf overlays it
  float* mbuf = (float*)smem;  // [128][68]
#pragma unroll
  for (int T = 0; T < 2; ++T) {
    const int row = qs + T * 16 + l15;
#pragma unroll
    for (int dt = 0; dt < 4; ++dt)
      *(float4v*)&mbuf[row * 68 + dt * 16 + l4 * 4] = oacc[T][dt];
    if (l4 == 0) pl[(size_t)(kr * 512 + pid) * 128 + row] = lT[T];
  }
  __syncthreads();  // order cross-lane LDS transpose
  float* pbase = po + (size_t)(kr * 512 + pid) * 8192 + qs * 64;
#pragma unroll
  for (int i = 0; i < 8; ++i) {
    const int e = i * 256 + lane * 4;   // within wave's 2048-f32 slice
    const int row = qs + (e >> 6), col = e & 63;
    *(float4v*)(pbase + e) = *(const float4v*)&mbuf[row * 68 + col];
  }
}

// ------- Stage E: combine the two key-range partials and normalize -------
__global__ __launch_bounds__(256) void comb(
    const float* __restrict__ po, const float* __restrict__ pl,
    float* __restrict__ out) {
  const int pid = blockIdx.x;            // 0..511
  const int t = threadIdx.x;
  const int qt = pid & 15, hb = pid >> 4;
  const int h = hb >> 1, bb = hb & 1;
  const float* p0 = po + (size_t)pid * 8192;
  const float* p1 = po + (size_t)(512 + pid) * 8192;
  const float* l0 = pl + (size_t)pid * 128;
  const float* l1 = pl + (size_t)(512 + pid) * 128;
#pragma unroll
  for (int i = 0; i < 8; ++i) {
    const int e = i * 1024 + t * 4;
    const int row = e >> 6, col = e & 63;
    float4v a = *(const float4v*)(p0 + e);
    const float4v bv = *(const float4v*)(p1 + e);
    const float li = 1.f / (l0[row] + l1[row]);
#pragma unroll
    for (int r = 0; r < 4; ++r) a[r] = (a[r] + bv[r]) * li;
    *(float4v*)(out + (size_t)(bb * S_ + qt * 128 + row) * D_ + h * HD_ + col) = a;
  }
}

extern "C" void kernel_launch(void* const* d_in, const int* in_sizes, int n_in,
                              void* d_out, int out_size, void* d_ws, size_t ws_size,
                              hipStream_t stream) {
  const float* hs = (const float*)d_in[0];
  const int* mask = (const int*)d_in[1];
  const float* Wq = (const float*)d_in[2];
  const float* bq = (const float*)d_in[3];
  const float* Wk = (const float*)d_in[4];
  const float* bk = (const float*)d_in[5];
  float* out = (float*)d_out;
  char* ws = (char*)d_ws;
  const size_t MB = 1u << 20;
  __hip_bfloat16* q_b = (__hip_bfloat16*)(ws + 0 * MB);   // [B,S,D] bf16, 8MB
  __hip_bfloat16* k_b = (__hip_bfloat16*)(ws + 8 * MB);   // softplus(k), 8MB
  __hip_bfloat16* vT  = (__hip_bfloat16*)(ws + 16 * MB);  // [B,H,HD,S] key-swizzled, 8MB
  __hip_bfloat16* Wqt = (__hip_bfloat16*)(ws + 24 * MB);  // 2MB
  __hip_bfloat16* Wkt = (__hip_bfloat16*)(ws + 26 * MB);  // 2MB
  __hip_bfloat16* hsb = (__hip_bfloat16*)(ws + 28 * MB);  // [B,S,D] bf16, 8MB
  // partials OVERLAY Wqt/Wkt/hsb (dead after gemm; stream-ordered):
  float* po = (float*)(ws + 24 * MB);                     // [2][512][8192] f32, 32MB
  float* pl = (float*)(ws + 56 * MB);                     // [2][512][128] f32, 512KB

  prep<<<dim3(2560), 256, 0, stream>>>(hs, hsb, Wq, Wk, Wqt, Wkt);
  gemm_fused<<<dim3(512), 256, 0, stream>>>(hsb, Wqt, Wkt, bq, bk, q_b, k_b, vT);
  attn<<<dim3(1024), 256, 0, stream>>>(q_b, k_b, vT, mask, po, pl);
  comb<<<dim3(512), 256, 0, stream>>>(po, pl, out);
}